// Round 1
// baseline (469.503 us; speedup 1.0000x reference)
//
#include <hip/hip_runtime.h>

typedef _Float16 f16;
typedef _Float16 half8 __attribute__((ext_vector_type(8)));
typedef _Float16 half4 __attribute__((ext_vector_type(4)));
typedef float float4_ __attribute__((ext_vector_type(4)));

#define MFMA16(a, b, c) __builtin_amdgcn_mfma_f32_16x16x32_f16(a, b, c, 0, 0, 0)

__device__ __forceinline__ void gld_lds16(const void* g, void* l) {
    __builtin_amdgcn_global_load_lds(
        (const __attribute__((address_space(1))) void*)g,
        (__attribute__((address_space(3))) void*)l, 16, 0, 0);
}

// ---------------- cast fp32 -> fp16 (optionally scale first `qboundary` elems)
__global__ void cast_kernel(const float* __restrict__ in, f16* __restrict__ out,
                            int n, int qboundary, float qscale) {
    int i = (blockIdx.x * blockDim.x + threadIdx.x) * 4;
    if (i >= n) return;
    float4_ v = *(const float4_*)(in + i);
    float sc = (i < qboundary) ? qscale : 1.0f;
    half4 h;
    h[0] = (f16)(v[0] * sc);
    h[1] = (f16)(v[1] * sc);
    h[2] = (f16)(v[2] * sc);
    h[3] = (f16)(v[3] * sc);
    *(half4*)(out + i) = h;
}

// ---------------- QKV GEMM: [8192,1024] x [3072,1024]^T, scatter to q/k/v [B,H,N,64]
__global__ __launch_bounds__(256, 2)
void qkv_gemm(const f16* __restrict__ X, const f16* __restrict__ W,
              f16* __restrict__ Q, f16* __restrict__ Kq, f16* __restrict__ V) {
    const int K = 1024;
    __shared__ __align__(16) f16 sA[128 * 64];
    __shared__ __align__(16) f16 sB[128 * 64];
    int tid = threadIdx.x;
    int lane = tid & 63, wave = tid >> 6;
    int wm = wave >> 1, wn = wave & 1;
    int l15 = lane & 15, quad = lane >> 4;
    int rowBase = blockIdx.y * 128;  // token index
    int colBase = blockIdx.x * 128;  // qkv dim index

    float4_ acc[4][4] = {};

    for (int k0 = 0; k0 < K; k0 += 64) {
        for (int i = 0; i < 4; ++i) {
            int seg = wave * 4 + i;
            int e = (seg * 64 + lane) * 8;
            int r = e >> 6, c = e & 63;
            gld_lds16(X + (size_t)(rowBase + r) * K + k0 + c, sA + seg * 512);
            gld_lds16(W + (size_t)(colBase + r) * K + k0 + c, sB + seg * 512);
        }
        __syncthreads();
        for (int ks = 0; ks < 2; ++ks) {
            half8 a[4], b[4];
            for (int mt = 0; mt < 4; ++mt)
                a[mt] = *(const half8*)&sA[(wm * 64 + mt * 16 + l15) * 64 + ks * 32 + quad * 8];
            for (int nt = 0; nt < 4; ++nt)
                b[nt] = *(const half8*)&sB[(wn * 64 + nt * 16 + l15) * 64 + ks * 32 + quad * 8];
            for (int mt = 0; mt < 4; ++mt)
                for (int nt = 0; nt < 4; ++nt)
                    acc[mt][nt] = MFMA16(a[mt], b[nt], acc[mt][nt]);
        }
        __syncthreads();
    }

    for (int mt = 0; mt < 4; ++mt) {
        int m0 = rowBase + wm * 64 + mt * 16 + quad * 4;
        for (int nt = 0; nt < 4; ++nt) {
            int d = colBase + wn * 64 + nt * 16 + l15;
            int part = d >> 10;
            int h = (d >> 6) & 15;
            int hd = d & 63;
            f16* dst = (part == 0) ? Q : (part == 1) ? Kq : V;
            for (int r = 0; r < 4; ++r) {
                int m = m0 + r;
                int b = m >> 11, n = m & 2047;
                dst[(size_t)((b * 16 + h) * 2048 + n) * 64 + hd] = (f16)acc[mt][nt][r];
            }
        }
    }
}

// ---------------- Flash attention: per (b,h), 128 q-rows per block, 64-key tiles
__global__ __launch_bounds__(256, 2)
void attn_kernel(const f16* __restrict__ Q, const f16* __restrict__ Kk,
                 const f16* __restrict__ V, f16* __restrict__ O) {
    const int bh = blockIdx.y;
    const int qt = blockIdx.x;
    const f16* Qb = Q + (size_t)bh * 2048 * 64;
    const f16* Kb = Kk + (size_t)bh * 2048 * 64;
    const f16* Vb = V + (size_t)bh * 2048 * 64;
    int tid = threadIdx.x, lane = tid & 63, wave = tid >> 6;
    int l15 = lane & 15, quad = lane >> 4;

    __shared__ __align__(16) f16 Vt[64 * 72];      // V^T [hd][key], stride 72 (16B aligned)
    __shared__ __align__(16) f16 Pl[4][32 * 72];   // per-wave P [row][key]

    int qrow = qt * 128 + wave * 32;
    half8 aQ[2][2];
    for (int mt = 0; mt < 2; ++mt)
        for (int kc = 0; kc < 2; ++kc)
            aQ[mt][kc] = *(const half8*)(Qb + (size_t)(qrow + mt * 16 + l15) * 64 + kc * 32 + quad * 8);

    float4_ oacc[2][4] = {};
    float mrow[2][4], lrow[2][4];
    for (int mt = 0; mt < 2; ++mt)
        for (int r = 0; r < 4; ++r) { mrow[mt][r] = -1e30f; lrow[mt][r] = 0.f; }

    f16* Pw = &Pl[wave][0];

    for (int t0 = 0; t0 < 2048; t0 += 64) {
        __syncthreads();  // previous iter's Vt/P fully consumed
        // stage V^T: wave stages hd rows [wave*16, wave*16+16), lane = key
        {
            const f16* vsrc = Vb + (size_t)(t0 + lane) * 64 + wave * 16;
            half8 v0 = *(const half8*)(vsrc);
            half8 v1 = *(const half8*)(vsrc + 8);
            for (int j = 0; j < 8; ++j) {
                Vt[(wave * 16 + j) * 72 + lane] = v0[j];
                Vt[(wave * 16 + 8 + j) * 72 + lane] = v1[j];
            }
        }
        // S = Q K^T (K fragments straight from global; rows are contiguous)
        float4_ s[2][4] = {};
        for (int kc = 0; kc < 2; ++kc) {
            half8 bK[4];
            for (int nt = 0; nt < 4; ++nt)
                bK[nt] = *(const half8*)(Kb + (size_t)(t0 + nt * 16 + l15) * 64 + kc * 32 + quad * 8);
            for (int mt = 0; mt < 2; ++mt)
                for (int nt = 0; nt < 4; ++nt)
                    s[mt][nt] = MFMA16(aQ[mt][kc], bK[nt], s[mt][nt]);
        }
        // online softmax (base-2 domain; scale*log2e folded into Wq)
        float alpha[2][4];
        for (int mt = 0; mt < 2; ++mt) {
            for (int r = 0; r < 4; ++r) {
                float mx = fmaxf(fmaxf(s[mt][0][r], s[mt][1][r]),
                                 fmaxf(s[mt][2][r], s[mt][3][r]));
                for (int off = 1; off < 16; off <<= 1)
                    mx = fmaxf(mx, __shfl_xor(mx, off, 64));
                float mnew = fmaxf(mrow[mt][r], mx);
                alpha[mt][r] = exp2f(mrow[mt][r] - mnew);
                mrow[mt][r] = mnew;
                float rs = 0.f;
                for (int nt = 0; nt < 4; ++nt) {
                    float p = exp2f(s[mt][nt][r] - mnew);
                    s[mt][nt][r] = p;
                    rs += p;
                }
                for (int off = 1; off < 16; off <<= 1)
                    rs += __shfl_xor(rs, off, 64);
                lrow[mt][r] = lrow[mt][r] * alpha[mt][r] + rs;
            }
        }
        // P -> per-wave LDS (C/D layout -> row-major [row][key])
        for (int mt = 0; mt < 2; ++mt)
            for (int nt = 0; nt < 4; ++nt)
                for (int r = 0; r < 4; ++r)
                    Pw[(mt * 16 + quad * 4 + r) * 72 + nt * 16 + l15] = (f16)s[mt][nt][r];
        // rescale O
        for (int mt = 0; mt < 2; ++mt)
            for (int ht = 0; ht < 4; ++ht)
                for (int r = 0; r < 4; ++r)
                    oacc[mt][ht][r] *= alpha[mt][r];
        __syncthreads();  // Vt staged by all waves; P visible
        // O += P V
        for (int kc = 0; kc < 2; ++kc) {
            half8 aP[2], bV[4];
            for (int mt = 0; mt < 2; ++mt)
                aP[mt] = *(const half8*)&Pw[(mt * 16 + l15) * 72 + kc * 32 + quad * 8];
            for (int ht = 0; ht < 4; ++ht)
                bV[ht] = *(const half8*)&Vt[(ht * 16 + l15) * 72 + kc * 32 + quad * 8];
            for (int mt = 0; mt < 2; ++mt)
                for (int ht = 0; ht < 4; ++ht)
                    oacc[mt][ht] = MFMA16(aP[mt], bV[ht], oacc[mt][ht]);
        }
    }
    // epilogue: O / l -> attn_out [B,N,C] fp16
    int b = bh >> 4, h = bh & 15;
    for (int mt = 0; mt < 2; ++mt) {
        for (int r = 0; r < 4; ++r) {
            float inv = 1.f / lrow[mt][r];
            int n = qrow + mt * 16 + quad * 4 + r;
            for (int ht = 0; ht < 4; ++ht) {
                int c = h * 64 + ht * 16 + l15;
                O[(size_t)(b * 2048 + n) * 1024 + c] = (f16)(oacc[mt][ht][r] * inv);
            }
        }
    }
}

// ---------------- Proj GEMM: [8192,1024] x [1024,1024]^T + bias -> fp32 out
__global__ __launch_bounds__(256, 2)
void proj_gemm(const f16* __restrict__ A, const f16* __restrict__ W,
               const float* __restrict__ bias, float* __restrict__ out) {
    const int K = 1024;
    __shared__ __align__(16) f16 sA[128 * 64];
    __shared__ __align__(16) f16 sB[128 * 64];
    int tid = threadIdx.x;
    int lane = tid & 63, wave = tid >> 6;
    int wm = wave >> 1, wn = wave & 1;
    int l15 = lane & 15, quad = lane >> 4;
    int rowBase = blockIdx.y * 128;
    int colBase = blockIdx.x * 128;

    float4_ acc[4][4] = {};

    for (int k0 = 0; k0 < K; k0 += 64) {
        for (int i = 0; i < 4; ++i) {
            int seg = wave * 4 + i;
            int e = (seg * 64 + lane) * 8;
            int r = e >> 6, c = e & 63;
            gld_lds16(A + (size_t)(rowBase + r) * K + k0 + c, sA + seg * 512);
            gld_lds16(W + (size_t)(colBase + r) * K + k0 + c, sB + seg * 512);
        }
        __syncthreads();
        for (int ks = 0; ks < 2; ++ks) {
            half8 a[4], b[4];
            for (int mt = 0; mt < 4; ++mt)
                a[mt] = *(const half8*)&sA[(wm * 64 + mt * 16 + l15) * 64 + ks * 32 + quad * 8];
            for (int nt = 0; nt < 4; ++nt)
                b[nt] = *(const half8*)&sB[(wn * 64 + nt * 16 + l15) * 64 + ks * 32 + quad * 8];
            for (int mt = 0; mt < 4; ++mt)
                for (int nt = 0; nt < 4; ++nt)
                    acc[mt][nt] = MFMA16(a[mt], b[nt], acc[mt][nt]);
        }
        __syncthreads();
    }

    for (int mt = 0; mt < 4; ++mt) {
        int m0 = rowBase + wm * 64 + mt * 16 + quad * 4;
        for (int nt = 0; nt < 4; ++nt) {
            int d = colBase + wn * 64 + nt * 16 + l15;
            float bv = bias[d];
            for (int r = 0; r < 4; ++r) {
                int m = m0 + r;
                out[(size_t)m * 1024 + d] = acc[mt][nt][r] + bv;
            }
        }
    }
}

extern "C" void kernel_launch(void* const* d_in, const int* in_sizes, int n_in,
                              void* d_out, int out_size, void* d_ws, size_t ws_size,
                              hipStream_t stream) {
    const float* x     = (const float*)d_in[0];
    const float* Wqkv  = (const float*)d_in[1];
    const float* Wproj = (const float*)d_in[2];
    const float* bproj = (const float*)d_in[3];
    float* out = (float*)d_out;

    f16* ws     = (f16*)d_ws;
    f16* xb     = ws;                    // 8388608
    f16* wqkvb  = xb + 8388608;          // 3145728
    f16* wprojb = wqkvb + 3145728;       // 1048576
    f16* q      = wprojb + 1048576;      // 8388608  [B,H,N,64]
    f16* k      = q + 8388608;           // 8388608
    f16* v      = k + 8388608;           // 8388608
    f16* ao     = v + 8388608;           // 8388608  [B,N,C]

    // qkv scale: 1/sqrt(64) * log2(e) folded into Q rows of W_qkv
    const float qscale = 0.125f * 1.4426950408889634f;

    cast_kernel<<<8192, 256, 0, stream>>>(x, xb, 8388608, 0, 1.f);
    cast_kernel<<<3072, 256, 0, stream>>>(Wqkv, wqkvb, 3145728, 1048576, qscale);
    cast_kernel<<<1024, 256, 0, stream>>>(Wproj, wprojb, 1048576, 0, 1.f);

    qkv_gemm<<<dim3(24, 64), 256, 0, stream>>>(xb, wqkvb, q, k, v);
    attn_kernel<<<dim3(16, 64), 256, 0, stream>>>(q, k, v, ao);
    proj_gemm<<<dim3(8, 64), 256, 0, stream>>>(ao, wprojb, bproj, out);
}